// Round 1
// baseline (454.876 us; speedup 1.0000x reference)
//
#include <hip/hip_runtime.h>
#include <hip/hip_bf16.h>

// NeuralODE: y_{s+1} = y_s + DT * (tanh(y W1 + b1) W2 + b2), 250 steps,
// snapshot every 5 steps -> out[8192][51][128] fp32.
//
// One wave per 16 rows (512 blocks x 64 thr), persistent over all 250 steps.
// Transposed chain: h^T = W1^T y^T (M=64,N=16rows,K=128), dy^T = W2^T h^T
// (M=128,N=16,K=64) with mfma_f32_16x16x32_bf16. Weight A-frags live in
// VGPRs for the whole kernel; y state lives in C-layout fp32 registers so
// the Euler update is pure register FMAs. C-layout -> B-operand transpose
// goes through padded wave-private LDS (b64 packed writes, b128 reads).

typedef __attribute__((ext_vector_type(8))) short bf16x8;   // 8 bf16 = 4 VGPRs
typedef __attribute__((ext_vector_type(4))) float floatx4;

static __device__ __forceinline__ short f2bf(float f) {
    unsigned u = __builtin_bit_cast(unsigned, f);
    u += 0x7fffu + ((u >> 16) & 1u);          // round-to-nearest-even
    return (short)(u >> 16);
}

static __device__ __forceinline__ unsigned pack2(float a, float b) {
    return (unsigned)(unsigned short)f2bf(a) |
           ((unsigned)(unsigned short)f2bf(b) << 16);
}

static __device__ __forceinline__ float tanh_fast(float x) {
    // tanh(x) = 1 - 2/(1 + e^{2x}); v_exp_f32 + v_rcp_f32, ~1ulp, saturates
    // correctly for |x| large (exp->inf -> rcp->0 -> 1; exp->0 -> -1).
    float e = __expf(2.0f * x);
    return 1.0f - 2.0f * __builtin_amdgcn_rcpf(1.0f + e);
}

#define YP 136   // LDS row stride for y tile, bf16 (128 + 8 pad: conflict-free)
#define HP 72    // LDS row stride for h tile, bf16 (64 + 8 pad)

__global__ __launch_bounds__(64, 1) void node_kernel(
    const float* __restrict__ x0, const float* __restrict__ W1,
    const float* __restrict__ b1, const float* __restrict__ W2,
    const float* __restrict__ b2, float* __restrict__ out)
{
    __shared__ __align__(16) unsigned short Yld[16 * YP];
    __shared__ __align__(16) unsigned short Hld[16 * HP];

    const int lane = threadIdx.x;
    const int n = lane & 15;        // row-within-tile == MFMA col (lane&15)
    const int q = lane >> 4;        // lane quad, 0..3
    const int row = (blockIdx.x << 4) + n;

    // ---- weight fragments: W1^T, W2^T as MFMA A-operands (loop-invariant) ----
    // A-layout: lane holds A[m = lane&15][k = 32*kt + 8*q + j], j=0..7
    bf16x8 w1f[4][4];               // [mt: hid/16][kt: d/32]; W1 is [128][64]
    #pragma unroll
    for (int mt = 0; mt < 4; ++mt) {
        #pragma unroll
        for (int kt = 0; kt < 4; ++kt) {
            const int m = mt * 16 + n;
            const int k0 = kt * 32 + q * 8;
            bf16x8 v;
            #pragma unroll
            for (int j = 0; j < 8; ++j) v[j] = f2bf(W1[(k0 + j) * 64 + m]);
            w1f[mt][kt] = v;
        }
    }
    bf16x8 w2f[8][2];               // [mt: d/16][kt: hid/32]; W2 is [64][128]
    #pragma unroll
    for (int mt = 0; mt < 8; ++mt) {
        #pragma unroll
        for (int kt = 0; kt < 2; ++kt) {
            const int m = mt * 16 + n;
            const int k0 = kt * 32 + q * 8;
            bf16x8 v;
            #pragma unroll
            for (int j = 0; j < 8; ++j) v[j] = f2bf(W2[(k0 + j) * 128 + m]);
            w2f[mt][kt] = v;
        }
    }

    // bias fragments in C-layout (row m = 4q+r within each 16-tile)
    floatx4 b1f[4], b2f[8];
    #pragma unroll
    for (int mt = 0; mt < 4; ++mt)
        #pragma unroll
        for (int r = 0; r < 4; ++r) b1f[mt][r] = b1[mt * 16 + q * 4 + r];
    #pragma unroll
    for (int mt = 0; mt < 8; ++mt)
        #pragma unroll
        for (int r = 0; r < 4; ++r) b2f[mt][r] = b2[mt * 16 + q * 4 + r];

    // ---- initial state: y0 = x0[row, 0, :, :] (128 fp32), C-layout regs ----
    // y[mt][r] = y[d = 16*mt + 4*q + r] of this lane's row n
    floatx4 y[8];
    #pragma unroll
    for (int mt = 0; mt < 8; ++mt)
        #pragma unroll
        for (int r = 0; r < 4; ++r)
            y[mt][r] = x0[row * 256 + mt * 16 + q * 4 + r];

    // write Y tile to LDS (bf16, B-operand feed for mm1)
    #pragma unroll
    for (int mt = 0; mt < 8; ++mt) {
        uint2 p;
        p.x = pack2(y[mt][0], y[mt][1]);
        p.y = pack2(y[mt][2], y[mt][3]);
        *reinterpret_cast<uint2*>(&Yld[n * YP + mt * 16 + q * 4]) = p;
    }
    // t = 0 snapshot
    #pragma unroll
    for (int mt = 0; mt < 8; ++mt)
        *reinterpret_cast<floatx4*>(out + (row * 51 + 0) * 128 + mt * 16 + q * 4) = y[mt];
    __syncthreads();

    for (int ti = 1; ti <= 50; ++ti) {
        #pragma unroll
        for (int ss = 0; ss < 5; ++ss) {
            // ---- mm1: h^T = W1^T * y^T + b1 ----
            bf16x8 yb[4];
            #pragma unroll
            for (int kt = 0; kt < 4; ++kt)
                yb[kt] = __builtin_bit_cast(bf16x8,
                    *reinterpret_cast<const uint4*>(&Yld[n * YP + kt * 32 + q * 8]));
            floatx4 acc[4];
            #pragma unroll
            for (int mt = 0; mt < 4; ++mt) acc[mt] = b1f[mt];
            #pragma unroll
            for (int kt = 0; kt < 4; ++kt)
                #pragma unroll
                for (int mt = 0; mt < 4; ++mt)
                    acc[mt] = __builtin_amdgcn_mfma_f32_16x16x32_bf16(
                        w1f[mt][kt], yb[kt], acc[mt], 0, 0, 0);

            // ---- tanh, pack to bf16, stage h tile in LDS ----
            #pragma unroll
            for (int mt = 0; mt < 4; ++mt) {
                float t0 = tanh_fast(acc[mt][0]);
                float t1 = tanh_fast(acc[mt][1]);
                float t2 = tanh_fast(acc[mt][2]);
                float t3 = tanh_fast(acc[mt][3]);
                uint2 p;
                p.x = pack2(t0, t1);
                p.y = pack2(t2, t3);
                *reinterpret_cast<uint2*>(&Hld[n * HP + mt * 16 + q * 4]) = p;
            }
            __syncthreads();

            // ---- mm2: dy^T = W2^T * h^T + b2 ----
            bf16x8 hb[2];
            #pragma unroll
            for (int kt = 0; kt < 2; ++kt)
                hb[kt] = __builtin_bit_cast(bf16x8,
                    *reinterpret_cast<const uint4*>(&Hld[n * HP + kt * 32 + q * 8]));
            floatx4 acc2[8];
            #pragma unroll
            for (int mt = 0; mt < 8; ++mt) acc2[mt] = b2f[mt];
            #pragma unroll
            for (int kt = 0; kt < 2; ++kt)
                #pragma unroll
                for (int mt = 0; mt < 8; ++mt)
                    acc2[mt] = __builtin_amdgcn_mfma_f32_16x16x32_bf16(
                        w2f[mt][kt], hb[kt], acc2[mt], 0, 0, 0);

            // ---- Euler update (pure regs) + restage Y tile ----
            #pragma unroll
            for (int mt = 0; mt < 8; ++mt) {
                #pragma unroll
                for (int r = 0; r < 4; ++r)
                    y[mt][r] = fmaf(0.001f, acc2[mt][r], y[mt][r]);
                uint2 p;
                p.x = pack2(y[mt][0], y[mt][1]);
                p.y = pack2(y[mt][2], y[mt][3]);
                *reinterpret_cast<uint2*>(&Yld[n * YP + mt * 16 + q * 4]) = p;
            }
            __syncthreads();
        }
        // ---- snapshot every 5 steps ----
        #pragma unroll
        for (int mt = 0; mt < 8; ++mt)
            *reinterpret_cast<floatx4*>(out + (row * 51 + ti) * 128 + mt * 16 + q * 4) = y[mt];
    }
}

extern "C" void kernel_launch(void* const* d_in, const int* in_sizes, int n_in,
                              void* d_out, int out_size, void* d_ws, size_t ws_size,
                              hipStream_t stream) {
    const float* x0 = (const float*)d_in[0];
    // d_in[1] = t grid: fixed 51 outputs x 5 substeps, unused
    const float* W1 = (const float*)d_in[2];
    const float* b1 = (const float*)d_in[3];
    const float* W2 = (const float*)d_in[4];
    const float* b2 = (const float*)d_in[5];
    float* out = (float*)d_out;

    node_kernel<<<dim3(512), dim3(64), 0, stream>>>(x0, W1, b1, W2, b2, out);
}

// Round 2
// 313.152 us; speedup vs baseline: 1.4526x; 1.4526x over previous
//
#include <hip/hip_runtime.h>
#include <hip/hip_bf16.h>

// NeuralODE: y_{s+1} = y_s + DT*(tanh(y W1 + b1) W2 + b2), 250 steps,
// snapshot every 5 -> out[8192][51][128] fp32.
//
// R2: split-m across a 4-wave workgroup. One 16-row tile per 256-thread
// block (512 blocks -> 2048 waves = 8 waves/CU, was 2). Wave w computes
// hidden cols [16w,16w+16) of mm1 and output cols [32w,32w+32) of mm2.
// Y/H tiles are broadcast through padded LDS (the C-layout -> B-operand
// transpose); 2 barriers per step. y state (32 cols x 16 rows per wave)
// stays in C-layout fp32 registers so Euler is pure register FMAs.

typedef __attribute__((ext_vector_type(8))) short bf16x8;   // 8 bf16 = 4 VGPRs
typedef __attribute__((ext_vector_type(4))) float floatx4;

static __device__ __forceinline__ short f2bf(float f) {
    unsigned u = __builtin_bit_cast(unsigned, f);
    u += 0x7fffu + ((u >> 16) & 1u);          // round-to-nearest-even
    return (short)(u >> 16);
}

static __device__ __forceinline__ unsigned pack2(float a, float b) {
    return (unsigned)(unsigned short)f2bf(a) |
           ((unsigned)(unsigned short)f2bf(b) << 16);
}

static __device__ __forceinline__ float tanh_fast(float x) {
    // tanh(x) = 1 - 2/(1+e^{2x}); exp->inf saturates to +1, exp->0 to -1.
    float e = __expf(2.0f * x);
    return 1.0f - 2.0f * __builtin_amdgcn_rcpf(1.0f + e);
}

#define YP 136   // LDS row stride (bf16) for Y tile: 128 + 8 pad
#define HP 72    // LDS row stride (bf16) for H tile: 64 + 8 pad

__global__ __launch_bounds__(256, 1) void node_kernel(
    const float* __restrict__ x0, const float* __restrict__ W1,
    const float* __restrict__ b1, const float* __restrict__ W2,
    const float* __restrict__ b2, float* __restrict__ out)
{
    __shared__ __align__(16) unsigned short Yld[16 * YP];
    __shared__ __align__(16) unsigned short Hld[16 * HP];

    const int tid  = threadIdx.x;
    const int w    = tid >> 6;          // wave id 0..3 (m-split owner)
    const int lane = tid & 63;
    const int n    = lane & 15;         // MFMA col == row-within-tile
    const int q    = lane >> 4;         // lane quad 0..3
    const int row  = (blockIdx.x << 4) + n;

    // ---- loop-invariant weight A-fragments (this wave's m-slices) ----
    // A-layout: lane holds A[m = 16*tile + n][k = 32*kt + 8*q + j], j=0..7
    bf16x8 w1f[4];                      // mm1: mt = w, kt = 0..3 (K=128)
    #pragma unroll
    for (int kt = 0; kt < 4; ++kt) {
        const int m  = w * 16 + n;
        const int k0 = kt * 32 + q * 8;
        bf16x8 v;
        #pragma unroll
        for (int j = 0; j < 8; ++j) v[j] = f2bf(W1[(k0 + j) * 64 + m]);
        w1f[kt] = v;
    }
    bf16x8 w2f[2][2];                   // mm2: mt = 2w+i, kt = 0..1 (K=64)
    #pragma unroll
    for (int i = 0; i < 2; ++i) {
        #pragma unroll
        for (int kt = 0; kt < 2; ++kt) {
            const int m  = w * 32 + i * 16 + n;
            const int k0 = kt * 32 + q * 8;
            bf16x8 v;
            #pragma unroll
            for (int j = 0; j < 8; ++j) v[j] = f2bf(W2[(k0 + j) * 128 + m]);
            w2f[i][kt] = v;
        }
    }

    // bias fragments in C-layout (row m = 4q+r within this wave's tiles)
    floatx4 b1f, b2f[2];
    #pragma unroll
    for (int r = 0; r < 4; ++r) b1f[r] = b1[w * 16 + q * 4 + r];
    #pragma unroll
    for (int i = 0; i < 2; ++i)
        #pragma unroll
        for (int r = 0; r < 4; ++r) b2f[i][r] = b2[w * 32 + i * 16 + q * 4 + r];

    // ---- y state: this wave's 32 d-columns of the 16-row tile ----
    // y[i][r] = y[d = 32w + 16i + 4q + r][row n]
    floatx4 y[2];
    #pragma unroll
    for (int i = 0; i < 2; ++i)
        #pragma unroll
        for (int r = 0; r < 4; ++r)
            y[i][r] = x0[row * 256 + w * 32 + i * 16 + q * 4 + r];

    // seed Y tile in LDS (bf16 B-operand feed) + t=0 snapshot
    #pragma unroll
    for (int i = 0; i < 2; ++i) {
        uint2 p;
        p.x = pack2(y[i][0], y[i][1]);
        p.y = pack2(y[i][2], y[i][3]);
        *reinterpret_cast<uint2*>(&Yld[n * YP + w * 32 + i * 16 + q * 4]) = p;
        *reinterpret_cast<floatx4*>(out + row * 51 * 128 + w * 32 + i * 16 + q * 4) = y[i];
    }
    __syncthreads();

    for (int ti = 1; ti <= 50; ++ti) {
        #pragma unroll
        for (int ss = 0; ss < 5; ++ss) {
            // ---- mm1 (this wave's 16 hidden cols): h^T = W1^T y^T + b1 ----
            bf16x8 yb[4];
            #pragma unroll
            for (int kt = 0; kt < 4; ++kt)
                yb[kt] = __builtin_bit_cast(bf16x8,
                    *reinterpret_cast<const uint4*>(&Yld[n * YP + kt * 32 + q * 8]));
            floatx4 acc = b1f;
            #pragma unroll
            for (int kt = 0; kt < 4; ++kt)
                acc = __builtin_amdgcn_mfma_f32_16x16x32_bf16(w1f[kt], yb[kt], acc, 0, 0, 0);

            // tanh + pack + stage this wave's H slice
            {
                float t0 = tanh_fast(acc[0]);
                float t1 = tanh_fast(acc[1]);
                float t2 = tanh_fast(acc[2]);
                float t3 = tanh_fast(acc[3]);
                uint2 p;
                p.x = pack2(t0, t1);
                p.y = pack2(t2, t3);
                *reinterpret_cast<uint2*>(&Hld[n * HP + w * 16 + q * 4]) = p;
            }
            __syncthreads();

            // ---- mm2 (this wave's 32 d cols): dy^T = W2^T h^T + b2 ----
            bf16x8 hb[2];
            #pragma unroll
            for (int kt = 0; kt < 2; ++kt)
                hb[kt] = __builtin_bit_cast(bf16x8,
                    *reinterpret_cast<const uint4*>(&Hld[n * HP + kt * 32 + q * 8]));
            floatx4 acc2[2] = { b2f[0], b2f[1] };
            #pragma unroll
            for (int kt = 0; kt < 2; ++kt)
                #pragma unroll
                for (int i = 0; i < 2; ++i)
                    acc2[i] = __builtin_amdgcn_mfma_f32_16x16x32_bf16(
                        w2f[i][kt], hb[kt], acc2[i], 0, 0, 0);

            // Euler update (pure regs) + restage Y slice
            #pragma unroll
            for (int i = 0; i < 2; ++i) {
                #pragma unroll
                for (int r = 0; r < 4; ++r)
                    y[i][r] = fmaf(0.001f, acc2[i][r], y[i][r]);
                uint2 p;
                p.x = pack2(y[i][0], y[i][1]);
                p.y = pack2(y[i][2], y[i][3]);
                *reinterpret_cast<uint2*>(&Yld[n * YP + w * 32 + i * 16 + q * 4]) = p;
            }
            __syncthreads();
        }
        // ---- snapshot every 5 steps ----
        #pragma unroll
        for (int i = 0; i < 2; ++i)
            *reinterpret_cast<floatx4*>(
                out + row * 51 * 128 + ti * 128 + w * 32 + i * 16 + q * 4) = y[i];
    }
}

extern "C" void kernel_launch(void* const* d_in, const int* in_sizes, int n_in,
                              void* d_out, int out_size, void* d_ws, size_t ws_size,
                              hipStream_t stream) {
    const float* x0 = (const float*)d_in[0];
    // d_in[1] = t grid: fixed 51 outputs x 5 substeps, unused
    const float* W1 = (const float*)d_in[2];
    const float* b1 = (const float*)d_in[3];
    const float* W2 = (const float*)d_in[4];
    const float* b2 = (const float*)d_in[5];
    float* out = (float*)d_out;

    node_kernel<<<dim3(512), dim3(256), 0, stream>>>(x0, W1, b1, W2, b2, out);
}